// Round 1
// baseline (487.907 us; speedup 1.0000x reference)
//
#include <hip/hip_runtime.h>
#include <hip/hip_bf16.h>
#include <cstdio>

// Problem constants (B=2, T=2048, D=1024, H=4096, O=1024, E=8, top-k=2)
#define NT_TOK 4096
#define D_DIM  1024
#define H_DIM  4096
#define O_DIM  1024
#define E_NUM  8
#define PAIRS  8192      // NT_TOK * 2
#define MT_SLOTS 64      // ceil(PAIRS / 128) worst-case m-tiles per expert

typedef short bf16x8 __attribute__((ext_vector_type(8)));
typedef float f32x4  __attribute__((ext_vector_type(4)));

// round-to-nearest-even fp32 -> bf16 bits
__device__ __forceinline__ unsigned short bfr(float f){
  unsigned u = __float_as_uint(f);
  unsigned r = (u + 0x7FFFu + ((u >> 16) & 1u)) >> 16;
  return (unsigned short)r;
}

// async global->LDS, 16B per lane; lds dest must be wave-uniform base (HW adds lane*16)
__device__ __forceinline__ void gload_lds16(const void* g, void* l){
  __builtin_amdgcn_global_load_lds((const __attribute__((address_space(1))) unsigned int*)g,
                                   (__attribute__((address_space(3))) unsigned int*)l,
                                   16, 0, 0);
}

// ---------------------------------------------------------------- cast x -> bf16
__global__ __launch_bounds__(256) void cast_x_kernel(const float* __restrict__ x,
                                                     unsigned short* __restrict__ xb){
  int i = blockIdx.x * 256 + threadIdx.x;           // over float4s: NT*D/4 = 1M
  const float4 v = ((const float4*)x)[i];
  unsigned short r0 = bfr(v.x), r1 = bfr(v.y), r2 = bfr(v.z), r3 = bfr(v.w);
  unsigned int p0 = (unsigned int)r0 | ((unsigned int)r1 << 16);
  unsigned int p1 = (unsigned int)r2 | ((unsigned int)r3 << 16);
  ((uint2*)xb)[i] = make_uint2(p0, p1);
}

// -------------------------------------------- cast+transpose [R][C] f32 -> [C][R] bf16
__global__ __launch_bounds__(256) void transpose_cast_kernel(const float* __restrict__ in,
                                                             unsigned short* __restrict__ out,
                                                             int R, int C){
  __shared__ float tile[32][33];
  long long base = (long long)blockIdx.z * R * C;
  int c0 = blockIdx.x * 32, r0 = blockIdx.y * 32;
  int tx = threadIdx.x, ty = threadIdx.y;           // 32 x 8
  #pragma unroll
  for (int i = 0; i < 4; i++)
    tile[ty + i*8][tx] = in[base + (long long)(r0 + ty + i*8) * C + c0 + tx];
  __syncthreads();
  #pragma unroll
  for (int i = 0; i < 4; i++)
    out[base + (long long)(c0 + ty + i*8) * R + r0 + tx] = bfr(tile[tx][ty + i*8]);
}

// ---------------------------------------------------------------- gating (top-2)
__global__ __launch_bounds__(256) void gating_kernel(const float* __restrict__ x,
                                                     const float* __restrict__ Wg,
                                                     const float* __restrict__ bg,
                                                     int*   __restrict__ pe,
                                                     float* __restrict__ pw){
  int wid = threadIdx.x >> 6, lane = threadIdx.x & 63;
  int t = blockIdx.x * 4 + wid;
  const float* xr = x + (long long)t * D_DIM;
  float acc[E_NUM];
  #pragma unroll
  for (int e = 0; e < E_NUM; e++) acc[e] = 0.f;
  for (int d = lane; d < D_DIM; d += 64){
    float xv = xr[d];
    const float* wr = Wg + d * E_NUM;
    #pragma unroll
    for (int e = 0; e < E_NUM; e++) acc[e] += xv * wr[e];
  }
  #pragma unroll
  for (int off = 32; off; off >>= 1)
    #pragma unroll
    for (int e = 0; e < E_NUM; e++) acc[e] += __shfl_xor(acc[e], off);
  if (lane == 0){
    float l[E_NUM];
    float m = -1e30f;
    #pragma unroll
    for (int e = 0; e < E_NUM; e++){ l[e] = acc[e] + bg[e]; m = fmaxf(m, l[e]); }
    float ex[E_NUM];
    #pragma unroll
    for (int e = 0; e < E_NUM; e++) ex[e] = expf(l[e] - m);
    int e0 = 0;
    #pragma unroll
    for (int e = 1; e < E_NUM; e++) if (ex[e] > ex[e0]) e0 = e;      // first max
    int e1 = (e0 == 0) ? 1 : 0;
    #pragma unroll
    for (int e = 0; e < E_NUM; e++) if (e != e0 && ex[e] > ex[e1] && e > -1){ if (e1 == e0 || ex[e] > ex[e1]) e1 = e; }
    // (re-scan cleanly for safety)
    e1 = -1;
    for (int e = 0; e < E_NUM; e++){ if (e == e0) continue; if (e1 < 0 || ex[e] > ex[e1]) e1 = e; }
    float s = ex[e0] + ex[e1];
    pe[2*t]   = e0;  pw[2*t]   = ex[e0] / s;
    pe[2*t+1] = e1;  pw[2*t+1] = ex[e1] / s;
  }
}

// ---------------------------------------------------------------- chunk histograms
__global__ __launch_bounds__(256) void hist_kernel(const int* __restrict__ pe,
                                                   int* __restrict__ chunk_hist){
  __shared__ int h[E_NUM];
  if (threadIdx.x < E_NUM) h[threadIdx.x] = 0;
  __syncthreads();
  int p = blockIdx.x * 256 + threadIdx.x;
  atomicAdd(&h[pe[p]], 1);
  __syncthreads();
  if (threadIdx.x < E_NUM) chunk_hist[blockIdx.x * E_NUM + threadIdx.x] = h[threadIdx.x];
}

// --------------------------------- scan + deterministic scatter into expert-sorted order
__global__ __launch_bounds__(256) void scatter_kernel(const int* __restrict__ pe,
                                                      const int* __restrict__ chunk_hist,
                                                      int* __restrict__ cnt,
                                                      int* __restrict__ offs,
                                                      int* __restrict__ row_pair){
  __shared__ int hist[32][E_NUM];
  __shared__ int pref[32][E_NUM];
  __shared__ int total[E_NUM];
  __shared__ int off_s[E_NUM + 1];
  __shared__ unsigned char ex[PAIRS];
  int tid = threadIdx.x;
  for (int i = tid; i < PAIRS; i += 256) ex[i] = (unsigned char)pe[i];
  { int c = tid >> 3, e = tid & 7; hist[c][e] = chunk_hist[tid]; }
  __syncthreads();
  if (tid < E_NUM){
    int s = 0;
    for (int c = 0; c < 32; c++){ pref[c][tid] = s; s += hist[c][tid]; }
    total[tid] = s;
  }
  __syncthreads();
  if (tid == 0){
    int s = 0;
    for (int e = 0; e < E_NUM; e++){ off_s[e] = s; s += total[e]; }
    off_s[E_NUM] = s;
  }
  __syncthreads();
  if (tid < E_NUM){ cnt[tid] = total[tid]; offs[tid] = off_s[tid]; }
  int c = tid >> 3, e = tid & 7;
  int base = off_s[e] + pref[c][e];
  int local = 0;
  for (int i = 0; i < 256; i++){
    int p = c * 256 + i;
    if (ex[p] == (unsigned char)e){
      row_pair[base + local] = p;
      local++;
    }
  }
}

// ---------------------------------------------------------------- grouped GEMM1
// hidden[pos][h] = relu( x[token(pos)] . W1[e][:, h] + b1[e][h] ), bf16 out
__global__ __launch_bounds__(256) void gemm1_kernel(const unsigned short* __restrict__ xb,
                                                    const unsigned short* __restrict__ W1t,
                                                    const float* __restrict__ b1,
                                                    const int* __restrict__ row_pair,
                                                    const int* __restrict__ cnt,
                                                    const int* __restrict__ offs,
                                                    unsigned short* __restrict__ hidden){
  int nt = blockIdx.x;                       // 0..31  (H/128)
  int e  = blockIdx.y >> 6;
  int mt = blockIdx.y & (MT_SLOTS - 1);
  int count = cnt[e];
  int m0 = mt * 128;
  if (m0 >= count) return;
  int seg = offs[e];
  int valid = count - m0;
  int n0 = nt * 128;

  __shared__ unsigned short As[128 * 64];
  __shared__ unsigned short Bs[128 * 64];
  int tid = threadIdx.x;
  int wid = tid >> 6, lane = tid & 63;
  int wr = wid >> 1, wc = wid & 1;

  const unsigned short* w1e = W1t + (long long)e * H_DIM * D_DIM;   // [H][D]

  const unsigned short* aptr[4];
  const unsigned short* bptr[4];
  #pragma unroll
  for (int i = 0; i < 4; i++){
    int c = wid * 4 + i;
    int r = c * 8 + (lane >> 3);
    int pos = seg + m0 + r; if (pos > PAIRS - 1) pos = PAIRS - 1;
    int token = row_pair[pos] >> 1;
    aptr[i] = xb  + (long long)token * D_DIM + ((lane & 7) * 8);
    bptr[i] = w1e + (long long)(n0 + r) * D_DIM + ((lane & 7) * 8);
  }

  f32x4 acc[4][4] = {};
  for (int kt = 0; kt < D_DIM / 64; ++kt){
    #pragma unroll
    for (int i = 0; i < 4; i++){
      int c = wid * 4 + i;
      gload_lds16(aptr[i], &As[c * 512]);  aptr[i] += 64;
      gload_lds16(bptr[i], &Bs[c * 512]);  bptr[i] += 64;
    }
    __syncthreads();
    #pragma unroll
    for (int ks = 0; ks < 2; ++ks){
      bf16x8 af[4], bfv[4];
      #pragma unroll
      for (int m = 0; m < 4; m++)
        af[m] = *(const bf16x8*)&As[(wr*64 + m*16 + (lane & 15)) * 64 + ks*32 + ((lane >> 4) * 8)];
      #pragma unroll
      for (int n = 0; n < 4; n++)
        bfv[n] = *(const bf16x8*)&Bs[(wc*64 + n*16 + (lane & 15)) * 64 + ks*32 + ((lane >> 4) * 8)];
      #pragma unroll
      for (int m = 0; m < 4; m++)
        #pragma unroll
        for (int n = 0; n < 4; n++)
          acc[m][n] = __builtin_amdgcn_mfma_f32_16x16x32_bf16(af[m], bfv[n], acc[m][n], 0, 0, 0);
    }
    __syncthreads();
  }

  const float* b1e = b1 + (long long)e * H_DIM;
  #pragma unroll
  for (int n = 0; n < 4; n++){
    int col = n0 + wc*64 + n*16 + (lane & 15);
    float bias = b1e[col];
    #pragma unroll
    for (int m = 0; m < 4; m++){
      int rl_base = wr*64 + m*16 + ((lane >> 4) << 2);
      #pragma unroll
      for (int j = 0; j < 4; j++){
        int rl = rl_base + j;
        if (rl < valid){
          float v = acc[m][n][j] + bias;
          v = v > 0.f ? v : 0.f;
          hidden[(long long)(seg + m0 + rl) * H_DIM + col] = bfr(v);
        }
      }
    }
  }
}

// ---------------------------------------------------------------- grouped GEMM2
// y_pair[p][o] = hidden[pos] . W2[e][:, o]   (bias+weight applied in combine)
__global__ __launch_bounds__(256) void gemm2_kernel(const unsigned short* __restrict__ hidden,
                                                    const unsigned short* __restrict__ W2t,
                                                    const int* __restrict__ row_pair,
                                                    const int* __restrict__ cnt,
                                                    const int* __restrict__ offs,
                                                    float* __restrict__ y){
  int nt = blockIdx.x;                       // 0..7  (O/128)
  int e  = blockIdx.y >> 6;
  int mt = blockIdx.y & (MT_SLOTS - 1);
  int count = cnt[e];
  int m0 = mt * 128;
  if (m0 >= count) return;
  int seg = offs[e];
  int valid = count - m0;
  int n0 = nt * 128;

  __shared__ unsigned short As[128 * 64];
  __shared__ unsigned short Bs[128 * 64];
  int tid = threadIdx.x;
  int wid = tid >> 6, lane = tid & 63;
  int wr = wid >> 1, wc = wid & 1;

  const unsigned short* w2e = W2t + (long long)e * O_DIM * H_DIM;   // [O][H]

  const unsigned short* aptr[4];
  const unsigned short* bptr[4];
  #pragma unroll
  for (int i = 0; i < 4; i++){
    int c = wid * 4 + i;
    int r = c * 8 + (lane >> 3);
    long long apos = seg + m0 + r; if (apos > PAIRS - 1) apos = PAIRS - 1;
    aptr[i] = hidden + apos * H_DIM + ((lane & 7) * 8);
    bptr[i] = w2e + (long long)(n0 + r) * H_DIM + ((lane & 7) * 8);
  }

  f32x4 acc[4][4] = {};
  for (int kt = 0; kt < H_DIM / 64; ++kt){
    #pragma unroll
    for (int i = 0; i < 4; i++){
      int c = wid * 4 + i;
      gload_lds16(aptr[i], &As[c * 512]);  aptr[i] += 64;
      gload_lds16(bptr[i], &Bs[c * 512]);  bptr[i] += 64;
    }
    __syncthreads();
    #pragma unroll
    for (int ks = 0; ks < 2; ++ks){
      bf16x8 af[4], bfv[4];
      #pragma unroll
      for (int m = 0; m < 4; m++)
        af[m] = *(const bf16x8*)&As[(wr*64 + m*16 + (lane & 15)) * 64 + ks*32 + ((lane >> 4) * 8)];
      #pragma unroll
      for (int n = 0; n < 4; n++)
        bfv[n] = *(const bf16x8*)&Bs[(wc*64 + n*16 + (lane & 15)) * 64 + ks*32 + ((lane >> 4) * 8)];
      #pragma unroll
      for (int m = 0; m < 4; m++)
        #pragma unroll
        for (int n = 0; n < 4; n++)
          acc[m][n] = __builtin_amdgcn_mfma_f32_16x16x32_bf16(af[m], bfv[n], acc[m][n], 0, 0, 0);
    }
    __syncthreads();
  }

  #pragma unroll
  for (int m = 0; m < 4; m++){
    int rl_base = wr*64 + m*16 + ((lane >> 4) << 2);
    #pragma unroll
    for (int j = 0; j < 4; j++){
      int rl = rl_base + j;
      if (rl < valid){
        int p = row_pair[seg + m0 + rl];
        float* yr = y + (long long)p * O_DIM;
        #pragma unroll
        for (int n = 0; n < 4; n++){
          int col = n0 + wc*64 + n*16 + (lane & 15);
          yr[col] = acc[m][n][j];
        }
      }
    }
  }
}

// ---------------------------------------------------------------- combine
__global__ __launch_bounds__(256) void combine_kernel(const float* __restrict__ y,
                                                      const float* __restrict__ b2,
                                                      const int* __restrict__ pe,
                                                      const float* __restrict__ pw,
                                                      float* __restrict__ out){
  int t = blockIdx.x, tid = threadIdx.x;      // 256 threads * float4 = 1024 = O_DIM
  int e0 = pe[2*t], e1 = pe[2*t+1];
  float w0 = pw[2*t], w1 = pw[2*t+1];
  const float4* y0 = (const float4*)(y + (long long)(2*t) * O_DIM);
  const float4* y1 = (const float4*)(y + (long long)(2*t+1) * O_DIM);
  const float4* c0 = (const float4*)(b2 + (long long)e0 * O_DIM);
  const float4* c1 = (const float4*)(b2 + (long long)e1 * O_DIM);
  float4 a = y0[tid], b = y1[tid], ca = c0[tid], cb = c1[tid];
  float4 r;
  r.x = w0 * (a.x + ca.x) + w1 * (b.x + cb.x);
  r.y = w0 * (a.y + ca.y) + w1 * (b.y + cb.y);
  r.z = w0 * (a.z + ca.z) + w1 * (b.z + cb.z);
  r.w = w0 * (a.w + ca.w) + w1 * (b.w + cb.w);
  ((float4*)(out + (long long)t * O_DIM))[tid] = r;
}

// ---------------------------------------------------------------- host
extern "C" void kernel_launch(void* const* d_in, const int* in_sizes, int n_in,
                              void* d_out, int out_size, void* d_ws, size_t ws_size,
                              hipStream_t stream){
  const float* x  = (const float*)d_in[0];
  const float* Wg = (const float*)d_in[1];
  const float* bg = (const float*)d_in[2];
  const float* W1 = (const float*)d_in[3];
  const float* b1 = (const float*)d_in[4];
  const float* W2 = (const float*)d_in[5];
  const float* b2 = (const float*)d_in[6];
  float* out = (float*)d_out;

  char* ws = (char*)d_ws;
  size_t off = 0;
  auto alloc = [&](size_t bytes){ size_t r = off; off += (bytes + 255) & ~(size_t)255; return r; };

  unsigned short* W1t    = (unsigned short*)(ws + alloc((size_t)E_NUM * H_DIM * D_DIM * 2));
  unsigned short* W2t    = (unsigned short*)(ws + alloc((size_t)E_NUM * O_DIM * H_DIM * 2));
  unsigned short* xb     = (unsigned short*)(ws + alloc((size_t)NT_TOK * D_DIM * 2));
  unsigned short* hidden = (unsigned short*)(ws + alloc((size_t)PAIRS * H_DIM * 2));
  float*          y_pair = (float*)         (ws + alloc((size_t)PAIRS * O_DIM * 4));
  int*            pe     = (int*)           (ws + alloc(PAIRS * 4));
  float*          pw     = (float*)         (ws + alloc(PAIRS * 4));
  int*            row_pair = (int*)         (ws + alloc(PAIRS * 4));
  int*            cnt    = (int*)           (ws + alloc(64));
  int*            offs   = (int*)           (ws + alloc(64));
  int*            chist  = (int*)           (ws + alloc(32 * E_NUM * 4));

  if (off > ws_size)
    fprintf(stderr, "kernel_launch: workspace too small: need %zu, have %zu\n", off, ws_size);

  cast_x_kernel<<<(NT_TOK * D_DIM / 4) / 256, 256, 0, stream>>>(x, xb);
  transpose_cast_kernel<<<dim3(H_DIM/32, D_DIM/32, E_NUM), dim3(32,8), 0, stream>>>(W1, W1t, D_DIM, H_DIM);
  transpose_cast_kernel<<<dim3(O_DIM/32, H_DIM/32, E_NUM), dim3(32,8), 0, stream>>>(W2, W2t, H_DIM, O_DIM);
  gating_kernel<<<NT_TOK/4, 256, 0, stream>>>(x, Wg, bg, pe, pw);
  hist_kernel<<<PAIRS/256, 256, 0, stream>>>(pe, chist);
  scatter_kernel<<<1, 256, 0, stream>>>(pe, chist, cnt, offs, row_pair);
  gemm1_kernel<<<dim3(H_DIM/128, E_NUM * MT_SLOTS), 256, 0, stream>>>(xb, W1t, b1, row_pair, cnt, offs, hidden);
  gemm2_kernel<<<dim3(O_DIM/128, E_NUM * MT_SLOTS), 256, 0, stream>>>(hidden, W2t, row_pair, cnt, offs, y_pair);
  combine_kernel<<<NT_TOK, 256, 0, stream>>>(y_pair, b2, pe, pw, out);
}